// Round 1
// baseline (5822.652 us; speedup 1.0000x reference)
//
#include <hip/hip_runtime.h>
#include <math.h>

#define NN   100000
#define NE   3200000
#define NEL  (NE + NN)   // edges + self loops
#define FEAT 128
#define HID  16
#define NCLS 20

// ---------------- embedding gather + MLP (relu(emb[id] @ W1 + b1)) ----------
__global__ __launch_bounds__(256) void k_embed_mlp(
    const int* __restrict__ ids, const float* __restrict__ emb,
    const float* __restrict__ W1, const float* __restrict__ b1,
    float* __restrict__ x0) {
  __shared__ float sW[FEAT * HID];
  for (int i = threadIdx.x; i < FEAT * HID; i += 256) sW[i] = W1[i];
  __syncthreads();
  int node = blockIdx.x * 16 + (threadIdx.x >> 4);
  int k = threadIdx.x & 15;
  if (node >= NN) return;
  int row = ids[node];
  const float* er = emb + (size_t)row * FEAT;
  float acc = b1[k];
#pragma unroll 8
  for (int j = 0; j < FEAT; ++j) acc = fmaf(er[j], sW[j * HID + k], acc);
  x0[(size_t)node * HID + k] = fmaxf(acc, 0.0f);
}

// ---------------- per-node normalize + zero accumulators --------------------
__global__ __launch_bounds__(256) void k_norm(
    const float* __restrict__ x, float* __restrict__ xn,
    float* __restrict__ s, float* __restrict__ xout) {
  int i = blockIdx.x * 256 + threadIdx.x;
  if (i >= NN) return;
  const float4* X = (const float4*)(x + (size_t)i * HID);
  float4 a = X[0], b = X[1], c = X[2], d = X[3];
  float n2 = a.x*a.x + a.y*a.y + a.z*a.z + a.w*a.w
           + b.x*b.x + b.y*b.y + b.z*b.z + b.w*b.w
           + c.x*c.x + c.y*c.y + c.z*c.z + c.w*c.w
           + d.x*d.x + d.y*d.y + d.z*d.z + d.w*d.w;
  float inv = 1.0f / fmaxf(sqrtf(n2), 1e-12f);
  float4* O = (float4*)(xn + (size_t)i * HID);
  O[0] = make_float4(a.x*inv, a.y*inv, a.z*inv, a.w*inv);
  O[1] = make_float4(b.x*inv, b.y*inv, b.z*inv, b.w*inv);
  O[2] = make_float4(c.x*inv, c.y*inv, c.z*inv, c.w*inv);
  O[3] = make_float4(d.x*inv, d.y*inv, d.z*inv, d.w*inv);
  s[i] = 0.0f;
  float4 z = make_float4(0.f, 0.f, 0.f, 0.f);
  float4* Z = (float4*)(xout + (size_t)i * HID);
  Z[0] = z; Z[1] = z; Z[2] = z; Z[3] = z;
}

// ---------------- edge pass A: e = exp(beta * cos), s[dst] += e -------------
// softmax is shift-invariant and alpha in [-|beta|, |beta|] (beta==1 here),
// so no segment_max needed: exp(alpha) is safely in [e^-1, e^1].
__global__ __launch_bounds__(256) void k_edge_e(
    const int* __restrict__ esrc, const int* __restrict__ edst,
    const float* __restrict__ xn, const float* __restrict__ beta_p,
    float* __restrict__ ebuf, float* __restrict__ s) {
  int e = blockIdx.x * 256 + threadIdx.x;
  if (e >= NEL) return;
  int u, v;
  if (e < NE) { u = esrc[e]; v = edst[e]; } else { u = e - NE; v = u; }
  float beta = beta_p ? beta_p[0] : 1.0f;
  const float4* A = (const float4*)(xn + (size_t)u * HID);
  const float4* B = (const float4*)(xn + (size_t)v * HID);
  float dsum = 0.0f;
#pragma unroll
  for (int r = 0; r < 4; ++r) {
    float4 av = A[r], bv = B[r];
    dsum += av.x*bv.x + av.y*bv.y + av.z*bv.z + av.w*bv.w;
  }
  float ev = __expf(beta * dsum);
  ebuf[e] = ev;
  atomicAdd(s + v, ev);
}

// ---------------- edge pass B: xout[dst] += (e/s[dst]) * x[src] -------------
__global__ __launch_bounds__(256) void k_scatter(
    const int* __restrict__ esrc, const int* __restrict__ edst,
    const float* __restrict__ x, const float* __restrict__ ebuf,
    const float* __restrict__ s, float* __restrict__ xout) {
  int e = blockIdx.x * 256 + threadIdx.x;
  if (e >= NEL) return;
  int u, v;
  if (e < NE) { u = esrc[e]; v = edst[e]; } else { u = e - NE; v = u; }
  float w = ebuf[e] / s[v];
  const float4* X = (const float4*)(x + (size_t)u * HID);
  float* o = xout + (size_t)v * HID;
#pragma unroll
  for (int r = 0; r < 4; ++r) {
    float4 xv = X[r];
    atomicAdd(o + 4*r + 0, w * xv.x);
    atomicAdd(o + 4*r + 1, w * xv.y);
    atomicAdd(o + 4*r + 2, w * xv.z);
    atomicAdd(o + 4*r + 3, w * xv.w);
  }
}

// ---------------- classifier + log_softmax ----------------------------------
__global__ __launch_bounds__(256) void k_cls(
    const float* __restrict__ x, const float* __restrict__ W2,
    const float* __restrict__ b2, float* __restrict__ out) {
  __shared__ float sW[HID * NCLS];
  __shared__ float sb[NCLS];
  for (int i = threadIdx.x; i < HID * NCLS; i += 256) sW[i] = W2[i];
  if (threadIdx.x < NCLS) sb[threadIdx.x] = b2[threadIdx.x];
  __syncthreads();
  int i = blockIdx.x * 256 + threadIdx.x;
  if (i >= NN) return;
  float xi[HID];
  const float4* X = (const float4*)(x + (size_t)i * HID);
#pragma unroll
  for (int r = 0; r < 4; ++r) {
    float4 v = X[r];
    xi[4*r+0] = v.x; xi[4*r+1] = v.y; xi[4*r+2] = v.z; xi[4*r+3] = v.w;
  }
  float logit[NCLS];
  float mx = -1e30f;
#pragma unroll
  for (int c = 0; c < NCLS; ++c) {
    float acc = sb[c];
#pragma unroll
    for (int k = 0; k < HID; ++k) acc = fmaf(xi[k], sW[k * NCLS + c], acc);
    logit[c] = acc;
    mx = fmaxf(mx, acc);
  }
  float ssum = 0.0f;
#pragma unroll
  for (int c = 0; c < NCLS; ++c) ssum += __expf(logit[c] - mx);
  float lse = mx + logf(ssum);
  float* o = out + (size_t)i * NCLS;
#pragma unroll
  for (int c = 0; c < NCLS; ++c) o[c] = logit[c] - lse;
}

extern "C" void kernel_launch(void* const* d_in, const int* in_sizes, int n_in,
                              void* d_out, int out_size, void* d_ws, size_t ws_size,
                              hipStream_t stream) {
  const int*   x_ids = (const int*)d_in[0];
  const int*   ei    = (const int*)d_in[1];   // [2, E]: row0 = src, row1 = dst
  const float* emb   = (const float*)d_in[2];
  const float* W1    = (const float*)d_in[3];
  const float* b1    = (const float*)d_in[4];
  const float* beta2 = (const float*)d_in[5];
  const float* W2    = (const float*)d_in[6];
  const float* b2    = (const float*)d_in[7];
  float* out = (float*)d_out;

  float* ws   = (float*)d_ws;
  float* x0   = ws;                          // [NN*HID]
  float* x1   = x0 + (size_t)NN * HID;       // [NN*HID]
  float* xn   = x1 + (size_t)NN * HID;       // [NN*HID]
  float* s    = xn + (size_t)NN * HID;       // [NN]
  float* ebuf = s + NN;                      // [NEL]

  const int* esrc = ei;
  const int* edst = ei + NE;

  const int gN  = (NN + 255) / 256;
  const int gE  = (NEL + 255) / 256;

  k_embed_mlp<<<(NN + 15) / 16, 256, 0, stream>>>(x_ids, emb, W1, b1, x0);

  // prop1 (beta = 1.0 fixed)
  k_norm<<<gN, 256, 0, stream>>>(x0, xn, s, x1);
  k_edge_e<<<gE, 256, 0, stream>>>(esrc, edst, xn, nullptr, ebuf, s);
  k_scatter<<<gE, 256, 0, stream>>>(esrc, edst, x0, ebuf, s, x1);

  // prop2 (beta = beta2, learnable)
  k_norm<<<gN, 256, 0, stream>>>(x1, xn, s, x0);
  k_edge_e<<<gE, 256, 0, stream>>>(esrc, edst, xn, beta2, ebuf, s);
  k_scatter<<<gE, 256, 0, stream>>>(esrc, edst, x1, ebuf, s, x0);

  k_cls<<<gN, 256, 0, stream>>>(x0, W2, b2, out);
}

// Round 2
// 521.628 us; speedup vs baseline: 11.1625x; 11.1625x over previous
//
#include <hip/hip_runtime.h>
#include <math.h>

#define NN    100000
#define NE    3200000
#define FEAT  128
#define HID   16
#define NCLS  20
#define NBLKA 391           // ceil(NN/256) blocks for the scan

// ---------------- embedding gather + MLP (relu(emb[id] @ W1 + b1)) ----------
__global__ __launch_bounds__(256) void k_embed_mlp(
    const int* __restrict__ ids, const float* __restrict__ emb,
    const float* __restrict__ W1, const float* __restrict__ b1,
    float* __restrict__ x0) {
  __shared__ float sW[FEAT * HID];
  for (int i = threadIdx.x; i < FEAT * HID; i += 256) sW[i] = W1[i];
  __syncthreads();
  int node = blockIdx.x * 16 + (threadIdx.x >> 4);
  int k = threadIdx.x & 15;
  if (node >= NN) return;
  int row = ids[node];
  const float* er = emb + (size_t)row * FEAT;
  float acc = b1[k];
#pragma unroll 8
  for (int j = 0; j < FEAT; ++j) acc = fmaf(er[j], sW[j * HID + k], acc);
  x0[(size_t)node * HID + k] = fmaxf(acc, 0.0f);
}

// ---------------- CSR build: zero / histogram / 3-pass scan / fill ----------
__global__ __launch_bounds__(256) void k_zero(int* __restrict__ c, int n) {
  int i = blockIdx.x * 256 + threadIdx.x;
  if (i < n) c[i] = 0;
}

__global__ __launch_bounds__(256) void k_hist(
    const int* __restrict__ edst, int* __restrict__ cnt) {
  int e = blockIdx.x * 256 + threadIdx.x;
  if (e >= NE) return;
  atomicAdd(cnt + edst[e], 1);
}

__global__ __launch_bounds__(256) void k_scanA(
    const int* __restrict__ cnt, int* __restrict__ rowptr, int* __restrict__ bsum) {
  __shared__ int sd[256];
  int tid = threadIdx.x;
  int i = blockIdx.x * 256 + tid;
  int v = (i < NN) ? cnt[i] : 0;
  sd[tid] = v;
  __syncthreads();
  for (int off = 1; off < 256; off <<= 1) {
    int t = (tid >= off) ? sd[tid - off] : 0;
    __syncthreads();
    sd[tid] += t;
    __syncthreads();
  }
  if (i < NN) rowptr[i] = sd[tid] - v;          // exclusive within block
  if (tid == 255) bsum[blockIdx.x] = sd[255];   // block total
}

__global__ __launch_bounds__(512) void k_scanB(
    const int* __restrict__ bsum, int* __restrict__ boff) {
  __shared__ int sd[512];
  int tid = threadIdx.x;
  int v = (tid < NBLKA) ? bsum[tid] : 0;
  sd[tid] = v;
  __syncthreads();
  for (int off = 1; off < 512; off <<= 1) {
    int t = (tid >= off) ? sd[tid - off] : 0;
    __syncthreads();
    sd[tid] += t;
    __syncthreads();
  }
  boff[tid] = sd[tid] - v;                      // exclusive block offsets
}

__global__ __launch_bounds__(256) void k_scanC(
    int* __restrict__ rowptr, const int* __restrict__ boff) {
  int i = blockIdx.x * 256 + threadIdx.x;
  if (i < NN) rowptr[i] += boff[i >> 8];
  if (i == 0) rowptr[NN] = NE;                  // total is compile-time known
}

__global__ __launch_bounds__(256) void k_fill(
    const int* __restrict__ esrc, const int* __restrict__ edst,
    const int* __restrict__ rowptr, int* __restrict__ wcnt,
    int* __restrict__ col) {
  int e = blockIdx.x * 256 + threadIdx.x;
  if (e >= NE) return;
  int v = edst[e];
  int pos = rowptr[v] + atomicAdd(wcnt + v, 1);
  col[pos] = esrc[e];
}

// ---------------- per-node normalize: xn = x/max(||x||,eps), nrm = max(||x||,eps)
__global__ __launch_bounds__(256) void k_norm(
    const float* __restrict__ x, float* __restrict__ xn, float* __restrict__ nrm) {
  int i = blockIdx.x * 256 + threadIdx.x;
  if (i >= NN) return;
  const float4* X = (const float4*)(x + (size_t)i * HID);
  float4 a = X[0], b = X[1], c = X[2], d = X[3];
  float n2 = a.x*a.x + a.y*a.y + a.z*a.z + a.w*a.w
           + b.x*b.x + b.y*b.y + b.z*b.z + b.w*b.w
           + c.x*c.x + c.y*c.y + c.z*c.z + c.w*c.w
           + d.x*d.x + d.y*d.y + d.z*d.z + d.w*d.w;
  float m = fmaxf(sqrtf(n2), 1e-12f);
  float inv = 1.0f / m;
  float4* O = (float4*)(xn + (size_t)i * HID);
  O[0] = make_float4(a.x*inv, a.y*inv, a.z*inv, a.w*inv);
  O[1] = make_float4(b.x*inv, b.y*inv, b.z*inv, b.w*inv);
  O[2] = make_float4(c.x*inv, c.y*inv, c.z*inv, c.w*inv);
  O[3] = make_float4(d.x*inv, d.y*inv, d.z*inv, d.w*inv);
  nrm[i] = m;                                   // x == xn*m (to 1 ulp)
}

// ---------------- fused AGNN prop (gather, no atomics) ----------------------
// out_i = sum_j e_ij * x_j / sum_j e_ij, with e_ij = exp(beta*dot(xn_i,xn_j)).
// 16 lanes per node, lane k owns feature k; dot via 4x shfl_xor in-group.
// Self-loop handled analytically (not in CSR).
__global__ __launch_bounds__(256) void k_prop(
    const int* __restrict__ rowptr, const int* __restrict__ col,
    const float* __restrict__ xn, const float* __restrict__ nrm,
    const float* __restrict__ beta_p, float* __restrict__ xout) {
  int node = blockIdx.x * 16 + (threadIdx.x >> 4);
  int k = threadIdx.x & 15;
  if (node >= NN) return;
  float beta = beta_p ? beta_p[0] : 1.0f;
  float xd = xn[(size_t)node * HID + k];
  // self edge: dot = ||xn_i||^2 (1 if nonzero row, 0 if zero row)
  float d = xd * xd;
  d += __shfl_xor(d, 1); d += __shfl_xor(d, 2);
  d += __shfl_xor(d, 4); d += __shfl_xor(d, 8);
  float ev = __expf(beta * d);
  float s = ev;
  float acc = ev * xd * nrm[node];
  int b = rowptr[node], e2 = rowptr[node + 1];
  int e = b;
  for (; e + 2 <= e2; e += 2) {                 // 2-way ILP
    int u0 = col[e], u1 = col[e + 1];
    float xu0 = xn[(size_t)u0 * HID + k];
    float xu1 = xn[(size_t)u1 * HID + k];
    float n0 = nrm[u0], n1 = nrm[u1];
    float d0 = xd * xu0, d1 = xd * xu1;
    d0 += __shfl_xor(d0, 1); d1 += __shfl_xor(d1, 1);
    d0 += __shfl_xor(d0, 2); d1 += __shfl_xor(d1, 2);
    d0 += __shfl_xor(d0, 4); d1 += __shfl_xor(d1, 4);
    d0 += __shfl_xor(d0, 8); d1 += __shfl_xor(d1, 8);
    float e0 = __expf(beta * d0), e1 = __expf(beta * d1);
    s += e0 + e1;
    acc += e0 * n0 * xu0 + e1 * n1 * xu1;
  }
  for (; e < e2; ++e) {
    int u = col[e];
    float xu = xn[(size_t)u * HID + k];
    float dd = xd * xu;
    dd += __shfl_xor(dd, 1); dd += __shfl_xor(dd, 2);
    dd += __shfl_xor(dd, 4); dd += __shfl_xor(dd, 8);
    float ee = __expf(beta * dd);
    s += ee;
    acc += ee * nrm[u] * xu;
  }
  xout[(size_t)node * HID + k] = acc / s;
}

// ---------------- classifier + log_softmax ----------------------------------
__global__ __launch_bounds__(256) void k_cls(
    const float* __restrict__ x, const float* __restrict__ W2,
    const float* __restrict__ b2, float* __restrict__ out) {
  __shared__ float sW[HID * NCLS];
  __shared__ float sb[NCLS];
  for (int i = threadIdx.x; i < HID * NCLS; i += 256) sW[i] = W2[i];
  if (threadIdx.x < NCLS) sb[threadIdx.x] = b2[threadIdx.x];
  __syncthreads();
  int i = blockIdx.x * 256 + threadIdx.x;
  if (i >= NN) return;
  float xi[HID];
  const float4* X = (const float4*)(x + (size_t)i * HID);
#pragma unroll
  for (int r = 0; r < 4; ++r) {
    float4 v = X[r];
    xi[4*r+0] = v.x; xi[4*r+1] = v.y; xi[4*r+2] = v.z; xi[4*r+3] = v.w;
  }
  float logit[NCLS];
  float mx = -1e30f;
#pragma unroll
  for (int c = 0; c < NCLS; ++c) {
    float acc = sb[c];
#pragma unroll
    for (int kk = 0; kk < HID; ++kk) acc = fmaf(xi[kk], sW[kk * NCLS + c], acc);
    logit[c] = acc;
    mx = fmaxf(mx, acc);
  }
  float ssum = 0.0f;
#pragma unroll
  for (int c = 0; c < NCLS; ++c) ssum += __expf(logit[c] - mx);
  float lse = mx + logf(ssum);
  float* o = out + (size_t)i * NCLS;
#pragma unroll
  for (int c = 0; c < NCLS; ++c) o[c] = logit[c] - lse;
}

extern "C" void kernel_launch(void* const* d_in, const int* in_sizes, int n_in,
                              void* d_out, int out_size, void* d_ws, size_t ws_size,
                              hipStream_t stream) {
  const int*   x_ids = (const int*)d_in[0];
  const int*   ei    = (const int*)d_in[1];   // [2, E]: row0 = src, row1 = dst
  const float* emb   = (const float*)d_in[2];
  const float* W1    = (const float*)d_in[3];
  const float* b1    = (const float*)d_in[4];
  const float* beta2 = (const float*)d_in[5];
  const float* W2    = (const float*)d_in[6];
  const float* b2    = (const float*)d_in[7];
  float* out = (float*)d_out;

  // workspace layout (all device scratch, re-initialized every call)
  float* ws   = (float*)d_ws;
  float* x0   = ws;                              // [NN*HID]  6.4 MB
  float* xn   = x0 + (size_t)NN * HID;           // [NN*HID]  6.4 MB
  float* nrm  = xn + (size_t)NN * HID;           // [NN]      0.4 MB
  int*   rowptr = (int*)(nrm + NN);              // [NN+1]
  int*   wcnt   = rowptr + (NN + 1);             // [NN] (hist cnt, then fill cursor)
  int*   bsum   = wcnt + NN;                     // [512]
  int*   boff   = bsum + 512;                    // [512]
  int*   col    = boff + 512;                    // [NE]     12.8 MB

  const int* esrc = ei;
  const int* edst = ei + NE;

  const int gN = (NN + 255) / 256;
  const int gE = (NE + 255) / 256;
  const int gP = (NN + 15) / 16;

  k_embed_mlp<<<gP, 256, 0, stream>>>(x_ids, emb, W1, b1, x0);

  // CSR over real edges (self-loops handled analytically in k_prop)
  k_zero<<<gN, 256, 0, stream>>>(wcnt, NN);
  k_hist<<<gE, 256, 0, stream>>>(edst, wcnt);
  k_scanA<<<NBLKA, 256, 0, stream>>>(wcnt, rowptr, bsum);
  k_scanB<<<1, 512, 0, stream>>>(bsum, boff);
  k_scanC<<<gN, 256, 0, stream>>>(rowptr, boff);
  k_zero<<<gN, 256, 0, stream>>>(wcnt, NN);
  k_fill<<<gE, 256, 0, stream>>>(esrc, edst, rowptr, wcnt, col);

  // prop1 (beta = 1.0 fixed)
  k_norm<<<gN, 256, 0, stream>>>(x0, xn, nrm);
  k_prop<<<gP, 256, 0, stream>>>(rowptr, col, xn, nrm, nullptr, x0);

  // prop2 (beta = beta2, learnable)
  k_norm<<<gN, 256, 0, stream>>>(x0, xn, nrm);
  k_prop<<<gP, 256, 0, stream>>>(rowptr, col, xn, nrm, beta2, x0);

  k_cls<<<gN, 256, 0, stream>>>(x0, W2, b2, out);
}

// Round 3
// 321.096 us; speedup vs baseline: 18.1337x; 1.6245x over previous
//
#include <hip/hip_runtime.h>
#include <math.h>

#define NN    100000
#define NE    3200000
#define FEAT  128
#define HID   16
#define NCLS  20
#define NBKT  391            // ceil(NN/256) coarse buckets (dst >> 8)
#define NBLKC 512            // blocks for bucket count/scatter passes

// ---------------- embedding gather + MLP (relu(emb[id] @ W1 + b1)) ----------
__global__ __launch_bounds__(256) void k_embed_mlp(
    const int* __restrict__ ids, const float* __restrict__ emb,
    const float* __restrict__ W1, const float* __restrict__ b1,
    float* __restrict__ x0) {
  __shared__ float sW[FEAT * HID];
  for (int i = threadIdx.x; i < FEAT * HID; i += 256) sW[i] = W1[i];
  __syncthreads();
  int node = blockIdx.x * 16 + (threadIdx.x >> 4);
  int k = threadIdx.x & 15;
  if (node >= NN) return;
  int row = ids[node];
  const float* er = emb + (size_t)row * FEAT;
  float acc = b1[k];
#pragma unroll 8
  for (int j = 0; j < FEAT; ++j) acc = fmaf(er[j], sW[j * HID + k], acc);
  x0[(size_t)node * HID + k] = fmaxf(acc, 0.0f);
}

// ---------------- CSR build: bucketed counting sort -------------------------
__global__ __launch_bounds__(256) void k_zero(int* __restrict__ c, int n) {
  int i = blockIdx.x * 256 + threadIdx.x;
  if (i < n) c[i] = 0;
}

// pass A: coarse bucket histogram, LDS-aggregated
__global__ __launch_bounds__(256) void kA(
    const int* __restrict__ edst, int* __restrict__ gcount) {
  __shared__ int h[NBKT];
  for (int i = threadIdx.x; i < NBKT; i += 256) h[i] = 0;
  __syncthreads();
  const int CH = (NE + NBLKC - 1) / NBLKC;
  int s0 = blockIdx.x * CH, s1 = min(NE, s0 + CH);
  for (int i = s0 + threadIdx.x; i < s1; i += 256)
    atomicAdd(&h[edst[i] >> 8], 1);
  __syncthreads();
  for (int i = threadIdx.x; i < NBKT; i += 256)
    if (h[i]) atomicAdd(&gcount[i], h[i]);
}

// pass B: scan bucket counts -> bases + cursors
__global__ __launch_bounds__(512) void kB(
    const int* __restrict__ gcount, int* __restrict__ gbase,
    int* __restrict__ gcur, int* __restrict__ rowptr) {
  __shared__ int sd[512];
  int tid = threadIdx.x;
  int v = (tid < NBKT) ? gcount[tid] : 0;
  sd[tid] = v;
  __syncthreads();
  for (int off = 1; off < 512; off <<= 1) {
    int t = (tid >= off) ? sd[tid - off] : 0;
    __syncthreads();
    sd[tid] += t;
    __syncthreads();
  }
  if (tid < NBKT) { int b = sd[tid] - v; gbase[tid] = b; gcur[tid] = b; }
  if (tid == 0) rowptr[NN] = NE;
}

// pass C: scatter packed (dstlow<<17 | src) into per-bucket streams.
// Each block reserves contiguous per-bucket sub-ranges -> line-contiguous writes.
__global__ __launch_bounds__(256) void kC(
    const int* __restrict__ esrc, const int* __restrict__ edst,
    int* __restrict__ gcur, unsigned* __restrict__ strm) {
  __shared__ int h[NBKT];
  __shared__ int basel[NBKT];
  for (int i = threadIdx.x; i < NBKT; i += 256) h[i] = 0;
  __syncthreads();
  const int CH = (NE + NBLKC - 1) / NBLKC;
  int s0 = blockIdx.x * CH, s1 = min(NE, s0 + CH);
  for (int i = s0 + threadIdx.x; i < s1; i += 256)
    atomicAdd(&h[edst[i] >> 8], 1);
  __syncthreads();
  for (int i = threadIdx.x; i < NBKT; i += 256) {
    int c = h[i];
    basel[i] = c ? atomicAdd(&gcur[i], c) : 0;
  }
  __syncthreads();
  for (int i = threadIdx.x; i < NBKT; i += 256) h[i] = 0;
  __syncthreads();
  for (int i = s0 + threadIdx.x; i < s1; i += 256) {
    int v = edst[i];
    int b = v >> 8;
    int p = basel[b] + atomicAdd(&h[b], 1);
    strm[p] = (unsigned)esrc[i] | ((unsigned)(v & 255) << 17);
  }
}

// pass D: one workgroup per bucket -> fine CSR via LDS hist + LDS scan.
// col writes stay in a ~32KB L2-resident window per bucket.
__global__ __launch_bounds__(256) void kD(
    const int* __restrict__ gcount, const int* __restrict__ gbase,
    const unsigned* __restrict__ strm, int* __restrict__ rowptr,
    int* __restrict__ col) {
  __shared__ int cnt[256];
  __shared__ int cur[256];
  __shared__ int sd[256];
  int b = blockIdx.x, tid = threadIdx.x;
  int base = gbase[b], n = gcount[b];
  cnt[tid] = 0;
  __syncthreads();
  for (int i = tid; i < n; i += 256)
    atomicAdd(&cnt[strm[base + i] >> 17], 1);
  __syncthreads();
  int v = cnt[tid];
  sd[tid] = v;
  __syncthreads();
  for (int off = 1; off < 256; off <<= 1) {
    int t = (tid >= off) ? sd[tid - off] : 0;
    __syncthreads();
    sd[tid] += t;
    __syncthreads();
  }
  int excl = sd[tid] - v;
  cur[tid] = excl;
  int node = (b << 8) + tid;
  if (node < NN) rowptr[node] = base + excl;
  __syncthreads();
  for (int i = tid; i < n; i += 256) {
    unsigned w = strm[base + i];
    int p = atomicAdd(&cur[w >> 17], 1);
    col[base + p] = (int)(w & 0x1FFFFu);
  }
}

// ---------------- fused AGNN prop (gather; norm recomputed in-register) -----
// out_i = (e_self*x_i + sum_j e_ij*x_j) / (e_self + sum_j e_ij)
// e_ij = exp(beta * (sum_k xn_i[k]*x_j[k]) * rsqrt(sum_k x_j[k]^2))
__global__ __launch_bounds__(256) void k_prop2(
    const int* __restrict__ rowptr, const int* __restrict__ col,
    const float* __restrict__ x, const float* __restrict__ beta_p,
    float* __restrict__ xout) {
  int node = blockIdx.x * 16 + (threadIdx.x >> 4);
  int k = threadIdx.x & 15;
  if (node >= NN) return;
  float beta = beta_p ? beta_p[0] : 1.0f;
  float xi = x[(size_t)node * HID + k];
  float n2 = xi * xi;
  n2 += __shfl_xor(n2, 1); n2 += __shfl_xor(n2, 2);
  n2 += __shfl_xor(n2, 4); n2 += __shfl_xor(n2, 8);
  float invi = rsqrtf(fmaxf(n2, 1e-24f));   // 1/max(||x_i||, 1e-12)
  float xdn = xi * invi;                    // xn_i[k]
  float dself = n2 * invi * invi;           // ||xn_i||^2 (==1 unless zero row)
  float es = __expf(beta * dself);
  float s = es;
  float acc = es * xi;
  int e = rowptr[node], e2 = rowptr[node + 1];
  for (; e + 2 <= e2; e += 2) {
    int u0 = col[e], u1 = col[e + 1];
    float a0 = x[(size_t)u0 * HID + k];
    float a1 = x[(size_t)u1 * HID + k];
    float r0 = xdn * a0, q0 = a0 * a0;
    float r1 = xdn * a1, q1 = a1 * a1;
    r0 += __shfl_xor(r0, 1); q0 += __shfl_xor(q0, 1);
    r1 += __shfl_xor(r1, 1); q1 += __shfl_xor(q1, 1);
    r0 += __shfl_xor(r0, 2); q0 += __shfl_xor(q0, 2);
    r1 += __shfl_xor(r1, 2); q1 += __shfl_xor(q1, 2);
    r0 += __shfl_xor(r0, 4); q0 += __shfl_xor(q0, 4);
    r1 += __shfl_xor(r1, 4); q1 += __shfl_xor(q1, 4);
    r0 += __shfl_xor(r0, 8); q0 += __shfl_xor(q0, 8);
    r1 += __shfl_xor(r1, 8); q1 += __shfl_xor(q1, 8);
    float e0 = __expf(beta * r0 * rsqrtf(fmaxf(q0, 1e-24f)));
    float e1 = __expf(beta * r1 * rsqrtf(fmaxf(q1, 1e-24f)));
    s += e0 + e1;
    acc += e0 * a0 + e1 * a1;
  }
  for (; e < e2; ++e) {
    int u = col[e];
    float a = x[(size_t)u * HID + k];
    float r = xdn * a, q = a * a;
    r += __shfl_xor(r, 1); q += __shfl_xor(q, 1);
    r += __shfl_xor(r, 2); q += __shfl_xor(q, 2);
    r += __shfl_xor(r, 4); q += __shfl_xor(q, 4);
    r += __shfl_xor(r, 8); q += __shfl_xor(q, 8);
    float ee = __expf(beta * r * rsqrtf(fmaxf(q, 1e-24f)));
    s += ee;
    acc += ee * a;
  }
  xout[(size_t)node * HID + k] = acc / s;
}

// ---------------- classifier + log_softmax ----------------------------------
__global__ __launch_bounds__(256) void k_cls(
    const float* __restrict__ x, const float* __restrict__ W2,
    const float* __restrict__ b2, float* __restrict__ out) {
  __shared__ float sW[HID * NCLS];
  __shared__ float sb[NCLS];
  for (int i = threadIdx.x; i < HID * NCLS; i += 256) sW[i] = W2[i];
  if (threadIdx.x < NCLS) sb[threadIdx.x] = b2[threadIdx.x];
  __syncthreads();
  int i = blockIdx.x * 256 + threadIdx.x;
  if (i >= NN) return;
  float xi[HID];
  const float4* X = (const float4*)(x + (size_t)i * HID);
#pragma unroll
  for (int r = 0; r < 4; ++r) {
    float4 v = X[r];
    xi[4*r+0] = v.x; xi[4*r+1] = v.y; xi[4*r+2] = v.z; xi[4*r+3] = v.w;
  }
  float logit[NCLS];
  float mx = -1e30f;
#pragma unroll
  for (int c = 0; c < NCLS; ++c) {
    float acc = sb[c];
#pragma unroll
    for (int kk = 0; kk < HID; ++kk) acc = fmaf(xi[kk], sW[kk * NCLS + c], acc);
    logit[c] = acc;
    mx = fmaxf(mx, acc);
  }
  float ssum = 0.0f;
#pragma unroll
  for (int c = 0; c < NCLS; ++c) ssum += __expf(logit[c] - mx);
  float lse = mx + logf(ssum);
  float* o = out + (size_t)i * NCLS;
#pragma unroll
  for (int c = 0; c < NCLS; ++c) o[c] = logit[c] - lse;
}

extern "C" void kernel_launch(void* const* d_in, const int* in_sizes, int n_in,
                              void* d_out, int out_size, void* d_ws, size_t ws_size,
                              hipStream_t stream) {
  const int*   x_ids = (const int*)d_in[0];
  const int*   ei    = (const int*)d_in[1];   // [2, E]: row0 = src, row1 = dst
  const float* emb   = (const float*)d_in[2];
  const float* W1    = (const float*)d_in[3];
  const float* b1    = (const float*)d_in[4];
  const float* beta2 = (const float*)d_in[5];
  const float* W2    = (const float*)d_in[6];
  const float* b2    = (const float*)d_in[7];
  float* out = (float*)d_out;

  // workspace layout (~26 MB). strm is dead after kD; x0/x1 alias it.
  unsigned* strm = (unsigned*)d_ws;                       // [NE] 12.8 MB
  float* x0 = (float*)d_ws;                               // [NN*HID] 6.4 MB (aliases strm)
  float* x1 = x0 + (size_t)NN * HID;                      // [NN*HID] 6.4 MB (aliases strm)
  int* col    = (int*)(strm + NE);                        // [NE] 12.8 MB
  int* rowptr = col + NE;                                 // [NN+1]
  int* gcount = rowptr + (NN + 1);                        // [NBKT]
  int* gbase  = gcount + NBKT;                            // [NBKT]
  int* gcur   = gbase + NBKT;                             // [NBKT]

  const int* esrc = ei;
  const int* edst = ei + NE;

  const int gN = (NN + 255) / 256;
  const int gP = (NN + 15) / 16;

  // CSR build (self-loops handled analytically in k_prop2)
  k_zero<<<2, 256, 0, stream>>>(gcount, NBKT);
  kA<<<NBLKC, 256, 0, stream>>>(edst, gcount);
  kB<<<1, 512, 0, stream>>>(gcount, gbase, gcur, rowptr);
  kC<<<NBLKC, 256, 0, stream>>>(esrc, edst, gcur, strm);
  kD<<<NBKT, 256, 0, stream>>>(gcount, gbase, strm, rowptr, col);

  // features (x0 reuses strm storage — strm dead after kD)
  k_embed_mlp<<<gP, 256, 0, stream>>>(x_ids, emb, W1, b1, x0);

  // prop1 (beta = 1.0 fixed), prop2 (beta = beta2)
  k_prop2<<<gP, 256, 0, stream>>>(rowptr, col, x0, nullptr, x1);
  k_prop2<<<gP, 256, 0, stream>>>(rowptr, col, x1, beta2, x0);

  k_cls<<<gN, 256, 0, stream>>>(x0, W2, b2, out);
}

// Round 4
// 264.489 us; speedup vs baseline: 22.0147x; 1.2140x over previous
//
#include <hip/hip_runtime.h>
#include <hip/hip_fp16.h>
#include <math.h>

#define NN    100000
#define NE    3200000
#define FEAT  128
#define HID   16
#define NCLS  20
#define NBKT  391            // ceil(NN/256) coarse buckets (dst >> 8)
#define NBLKC 512            // blocks for bucket count/scatter passes

// ---- embedding gather + MLP -> fp16 features + invn ------------------------
__global__ __launch_bounds__(256) void k_embed_mlp(
    const int* __restrict__ ids, const float* __restrict__ emb,
    const float* __restrict__ W1, const float* __restrict__ b1,
    __half* __restrict__ hx, float* __restrict__ invn) {
  __shared__ float sW[FEAT * HID];
  for (int i = threadIdx.x; i < FEAT * HID; i += 256) sW[i] = W1[i];
  __syncthreads();
  int node = blockIdx.x * 16 + (threadIdx.x >> 4);
  int k = threadIdx.x & 15;
  if (node >= NN) return;
  const float* er = emb + (size_t)ids[node] * FEAT;
  float acc = b1[k];
#pragma unroll 8
  for (int j = 0; j < FEAT; ++j) acc = fmaf(er[j], sW[j * HID + k], acc);
  acc = fmaxf(acc, 0.0f);
  __half h = __float2half(acc);
  float a = __half2float(h);
  float n2 = a * a;
  n2 += __shfl_xor(n2, 1); n2 += __shfl_xor(n2, 2);
  n2 += __shfl_xor(n2, 4); n2 += __shfl_xor(n2, 8);
  hx[node * HID + k] = h;
  if (k == 0) invn[node] = rsqrtf(fmaxf(n2, 1e-24f));  // 1/max(||x||,1e-12)
}

// ---------------- CSR build: bucketed counting sort -------------------------
__global__ __launch_bounds__(256) void k_zero(int* __restrict__ c, int n) {
  int i = blockIdx.x * 256 + threadIdx.x;
  if (i < n) c[i] = 0;
}

__global__ __launch_bounds__(256) void kA(
    const int* __restrict__ edst, int* __restrict__ gcount) {
  __shared__ int h[NBKT];
  for (int i = threadIdx.x; i < NBKT; i += 256) h[i] = 0;
  __syncthreads();
  const int CH = (NE + NBLKC - 1) / NBLKC;
  int s0 = blockIdx.x * CH, s1 = min(NE, s0 + CH);
  for (int i = s0 + threadIdx.x; i < s1; i += 256)
    atomicAdd(&h[edst[i] >> 8], 1);
  __syncthreads();
  for (int i = threadIdx.x; i < NBKT; i += 256)
    if (h[i]) atomicAdd(&gcount[i], h[i]);
}

__global__ __launch_bounds__(512) void kB(
    const int* __restrict__ gcount, int* __restrict__ gbase,
    int* __restrict__ gcur, int* __restrict__ rowptr) {
  __shared__ int sd[512];
  int tid = threadIdx.x;
  int v = (tid < NBKT) ? gcount[tid] : 0;
  sd[tid] = v;
  __syncthreads();
  for (int off = 1; off < 512; off <<= 1) {
    int t = (tid >= off) ? sd[tid - off] : 0;
    __syncthreads();
    sd[tid] += t;
    __syncthreads();
  }
  if (tid < NBKT) { int b = sd[tid] - v; gbase[tid] = b; gcur[tid] = b; }
  if (tid == 0) rowptr[NN] = NE;
}

__global__ __launch_bounds__(256) void kC(
    const int* __restrict__ esrc, const int* __restrict__ edst,
    int* __restrict__ gcur, unsigned* __restrict__ strm) {
  __shared__ int h[NBKT];
  __shared__ int basel[NBKT];
  for (int i = threadIdx.x; i < NBKT; i += 256) h[i] = 0;
  __syncthreads();
  const int CH = (NE + NBLKC - 1) / NBLKC;
  int s0 = blockIdx.x * CH, s1 = min(NE, s0 + CH);
  for (int i = s0 + threadIdx.x; i < s1; i += 256)
    atomicAdd(&h[edst[i] >> 8], 1);
  __syncthreads();
  for (int i = threadIdx.x; i < NBKT; i += 256) {
    int c = h[i];
    basel[i] = c ? atomicAdd(&gcur[i], c) : 0;
  }
  __syncthreads();
  for (int i = threadIdx.x; i < NBKT; i += 256) h[i] = 0;
  __syncthreads();
  for (int i = s0 + threadIdx.x; i < s1; i += 256) {
    int v = edst[i];
    int b = v >> 8;
    int p = basel[b] + atomicAdd(&h[b], 1);
    strm[p] = (unsigned)esrc[i] | ((unsigned)(v & 255) << 17);
  }
}

__global__ __launch_bounds__(256) void kD(
    const int* __restrict__ gcount, const int* __restrict__ gbase,
    const unsigned* __restrict__ strm, int* __restrict__ rowptr,
    int* __restrict__ col) {
  __shared__ int cnt[256];
  __shared__ int cur[256];
  __shared__ int sd[256];
  int b = blockIdx.x, tid = threadIdx.x;
  int base = gbase[b], n = gcount[b];
  cnt[tid] = 0;
  __syncthreads();
  for (int i = tid; i < n; i += 256)
    atomicAdd(&cnt[strm[base + i] >> 17], 1);
  __syncthreads();
  int v = cnt[tid];
  sd[tid] = v;
  __syncthreads();
  for (int off = 1; off < 256; off <<= 1) {
    int t = (tid >= off) ? sd[tid - off] : 0;
    __syncthreads();
    sd[tid] += t;
    __syncthreads();
  }
  int excl = sd[tid] - v;
  cur[tid] = excl;
  int node = (b << 8) + tid;
  if (node < NN) rowptr[node] = base + excl;
  __syncthreads();
  for (int i = tid; i < n; i += 256) {
    unsigned w = strm[base + i];
    int p = atomicAdd(&cur[w >> 17], 1);
    col[base + p] = (int)(w & 0x1FFFFu);
  }
}

// ---- fused AGNN prop: fp16 gathers + invn table, emits fp16 + invn ---------
// out_i = (e_self*x_i + sum_j e_ij*x_j) / (e_self + sum_j e_ij)
// e_ij = exp(beta * (sum_k xn_i[k]*x_j[k]) * invn_j)
__global__ __launch_bounds__(256) void k_prop(
    const int* __restrict__ rowptr, const int* __restrict__ col,
    const __half* __restrict__ hx, const float* __restrict__ invn,
    const float* __restrict__ beta_p,
    __half* __restrict__ hxo, float* __restrict__ invno) {
  int node = blockIdx.x * 16 + (threadIdx.x >> 4);
  int k = threadIdx.x & 15;
  if (node >= NN) return;
  float beta = beta_p ? beta_p[0] : 1.0f;
  float xi = __half2float(hx[node * HID + k]);
  float invi = invn[node];
  float n2 = xi * xi;
  n2 += __shfl_xor(n2, 1); n2 += __shfl_xor(n2, 2);
  n2 += __shfl_xor(n2, 4); n2 += __shfl_xor(n2, 8);
  float xdn = xi * invi;                  // xn_i[k]
  float dself = n2 * invi * invi;         // ||xn_i||^2
  float es = __expf(beta * dself);
  float s = es;
  float acc = es * xi;
  int e = rowptr[node], e2 = rowptr[node + 1];
  for (; e + 2 <= e2; e += 2) {
    int u0 = col[e], u1 = col[e + 1];
    float a0 = __half2float(hx[u0 * HID + k]);
    float a1 = __half2float(hx[u1 * HID + k]);
    float i0 = invn[u0], i1 = invn[u1];
    float r0 = xdn * a0, r1 = xdn * a1;
    r0 += __shfl_xor(r0, 1); r1 += __shfl_xor(r1, 1);
    r0 += __shfl_xor(r0, 2); r1 += __shfl_xor(r1, 2);
    r0 += __shfl_xor(r0, 4); r1 += __shfl_xor(r1, 4);
    r0 += __shfl_xor(r0, 8); r1 += __shfl_xor(r1, 8);
    float e0 = __expf(beta * r0 * i0);
    float e1 = __expf(beta * r1 * i1);
    s += e0 + e1;
    acc += e0 * a0 + e1 * a1;
  }
  for (; e < e2; ++e) {
    int u = col[e];
    float a = __half2float(hx[u * HID + k]);
    float r = xdn * a;
    r += __shfl_xor(r, 1); r += __shfl_xor(r, 2);
    r += __shfl_xor(r, 4); r += __shfl_xor(r, 8);
    float ee = __expf(beta * r * invn[u]);
    s += ee;
    acc += ee * a;
  }
  __half oh = __float2half(acc / s);
  float of = __half2float(oh);
  float m2 = of * of;
  m2 += __shfl_xor(m2, 1); m2 += __shfl_xor(m2, 2);
  m2 += __shfl_xor(m2, 4); m2 += __shfl_xor(m2, 8);
  hxo[node * HID + k] = oh;
  if (k == 0) invno[node] = rsqrtf(fmaxf(m2, 1e-24f));
}

// ---------------- classifier + log_softmax (fp16 input) ---------------------
__global__ __launch_bounds__(256) void k_cls(
    const __half* __restrict__ x, const float* __restrict__ W2,
    const float* __restrict__ b2, float* __restrict__ out) {
  __shared__ float sW[HID * NCLS];
  __shared__ float sb[NCLS];
  for (int i = threadIdx.x; i < HID * NCLS; i += 256) sW[i] = W2[i];
  if (threadIdx.x < NCLS) sb[threadIdx.x] = b2[threadIdx.x];
  __syncthreads();
  int i = blockIdx.x * 256 + threadIdx.x;
  if (i >= NN) return;
  float xi[HID];
  const __half2* X = (const __half2*)(x + (size_t)i * HID);
#pragma unroll
  for (int r = 0; r < 8; ++r) {
    float2 f = __half22float2(X[r]);
    xi[2 * r] = f.x; xi[2 * r + 1] = f.y;
  }
  float logit[NCLS];
  float mx = -1e30f;
#pragma unroll
  for (int c = 0; c < NCLS; ++c) {
    float acc = sb[c];
#pragma unroll
    for (int kk = 0; kk < HID; ++kk) acc = fmaf(xi[kk], sW[kk * NCLS + c], acc);
    logit[c] = acc;
    mx = fmaxf(mx, acc);
  }
  float ssum = 0.0f;
#pragma unroll
  for (int c = 0; c < NCLS; ++c) ssum += __expf(logit[c] - mx);
  float lse = mx + logf(ssum);
  float* o = out + (size_t)i * NCLS;
#pragma unroll
  for (int c = 0; c < NCLS; ++c) o[c] = logit[c] - lse;
}

extern "C" void kernel_launch(void* const* d_in, const int* in_sizes, int n_in,
                              void* d_out, int out_size, void* d_ws, size_t ws_size,
                              hipStream_t stream) {
  const int*   x_ids = (const int*)d_in[0];
  const int*   ei    = (const int*)d_in[1];   // [2, E]: row0 = src, row1 = dst
  const float* emb   = (const float*)d_in[2];
  const float* W1    = (const float*)d_in[3];
  const float* b1    = (const float*)d_in[4];
  const float* beta2 = (const float*)d_in[5];
  const float* W2    = (const float*)d_in[6];
  const float* b2    = (const float*)d_in[7];
  float* out = (float*)d_out;

  // workspace: [strm NE u32 | col NE | rowptr | gcount | gbase | gcur]
  // strm is dead after kD; fp16 feature pipeline aliases it (7.2 MB < 12.8 MB).
  unsigned* strm = (unsigned*)d_ws;
  int* col    = (int*)d_ws + NE;
  int* rowptr = col + NE;
  int* gcount = rowptr + (NN + 1);
  int* gbase  = gcount + NBKT;
  int* gcur   = gbase + NBKT;
  __half* hx0   = (__half*)d_ws;                 // [NN*HID] 3.2 MB
  __half* hx1   = hx0 + (size_t)NN * HID;        // [NN*HID] 3.2 MB
  float*  invn0 = (float*)(hx1 + (size_t)NN * HID);  // [NN] 0.4 MB
  float*  invn1 = invn0 + NN;                    // [NN] 0.4 MB

  const int* esrc = ei;
  const int* edst = ei + NE;

  const int gN = (NN + 255) / 256;
  const int gP = (NN + 15) / 16;

  // CSR build (self-loops handled analytically in k_prop)
  k_zero<<<2, 256, 0, stream>>>(gcount, NBKT);
  kA<<<NBLKC, 256, 0, stream>>>(edst, gcount);
  kB<<<1, 512, 0, stream>>>(gcount, gbase, gcur, rowptr);
  kC<<<NBLKC, 256, 0, stream>>>(esrc, edst, gcur, strm);
  kD<<<NBKT, 256, 0, stream>>>(gcount, gbase, strm, rowptr, col);

  // features (fp16 + invn), aliasing strm (dead after kD)
  k_embed_mlp<<<gP, 256, 0, stream>>>(x_ids, emb, W1, b1, hx0, invn0);

  // prop1 (beta = 1.0), prop2 (beta = beta2)
  k_prop<<<gP, 256, 0, stream>>>(rowptr, col, hx0, invn0, nullptr, hx1, invn1);
  k_prop<<<gP, 256, 0, stream>>>(rowptr, col, hx1, invn1, beta2, hx0, invn0);

  k_cls<<<gN, 256, 0, stream>>>(hx0, W2, b2, out);
}